// Round 7
// baseline (811.651 us; speedup 1.0000x reference)
//
#include <hip/hip_runtime.h>
#include <float.h>

// MAM dense, fused. C[m,n] = max_k(A[m,k]*W[n,k]) + min_k + bias[n] + arg
// indices (numpy first-occurrence).
//
// R7 = R6 with the W-read base fix. R6 failed because the read-side base for
// W omitted the +16384 A-region offset (DMA dest had it, read didn't) -> W
// fragments were read from the A region. DMA-dest and read-base are a PAIR.
//
// R6 experiment (unchanged otherwise): 512-thread blocks (BM=128 x BN=64),
// same 4x4/thread tile as R5. Block-residency stuck at ~2.5 blocks/CU across
// R1/R4/R5 regardless of headroom -> put 8 waves in each block to raise
// waves/CU 10 -> ~16. Inner loop identical per thread.
//  - Quad-major LDS [buf][A: quad8][row128][4f] @0 + [W: quad8][row64][4f]
//    @16384: every ds_read address = base + compile-time imm; <=2-way
//    conflicts (R5 measured 0). 48KB/block double-buffered.
//  - DMA global_load_lds width=16, linear dest (rule 21), one quad per wave;
//    sibling waves fetch neighboring quads of the same 64B line in the same
//    phase -> L2 dedups (R5: FETCH 237MB).
//  - Window-8 tracking: c=max3(c,q.x,q.y) chain, one max3/min3 per pk_mul;
//    (c != vmax) -> wnd. Ties keep earlier window = first occurrence.
//    Epilogue re-reads the winning 8-k window from global (L2/L3-hot),
//    ascending scan, bitwise-identical products (proven R3-R5).

typedef float f32x2 __attribute__((ext_vector_type(2)));
typedef float f32x4 __attribute__((ext_vector_type(4)));

#define BM 128
#define BN 64
#define BK 32

__device__ __forceinline__ f32x2 pk_mul(f32x2 a, f32x2 b) {
  f32x2 d;
  asm("v_pk_mul_f32 %0, %1, %2" : "=v"(d) : "v"(a), "v"(b));
  return d;
}
__device__ __forceinline__ float vmax3(float a, float b, float c) {
  float d;
  asm("v_max3_f32 %0, %1, %2, %3" : "=v"(d) : "v"(a), "v"(b), "v"(c));
  return d;
}
__device__ __forceinline__ float vmin3(float a, float b, float c) {
  float d;
  asm("v_min3_f32 %0, %1, %2, %3" : "=v"(d) : "v"(a), "v"(b), "v"(c));
  return d;
}

#define GLOAD16(gp, lp)                                                \
  __builtin_amdgcn_global_load_lds(                                    \
      (const __attribute__((address_space(1))) unsigned int*)(gp),     \
      (__attribute__((address_space(3))) unsigned int*)(lp), 16, 0, 0)

__global__ __launch_bounds__(512, 2)
void mam_fused(const float* __restrict__ A, const float* __restrict__ W,
               const float* __restrict__ bias,
               float* __restrict__ out_v, float* __restrict__ out_ax,
               float* __restrict__ out_an, int M, int N, int K) {
  // per buf: A [quad8][row128][4f] = 16384B @0, W [quad8][row64][4f] = 8192B
  // @16384. buf stride 24576B; total 49152B.
  __shared__ __align__(16) unsigned char pool[49152];

  const int tid = threadIdx.x;
  const int tx = tid & 15;  // n-group: cols tx, tx+16, tx+32, tx+48
  const int ty = tid >> 4;  // m-group: rows ty*4 .. ty*4+3  (0..31)
  const int m0 = blockIdx.y * BM;
  const int n0 = blockIdx.x * BN;

  // ---- DMA mapping: wave wv owns quad wv; lane ln = row ----
  const int wv = tid >> 6;  // 0..7
  const int ln = tid & 63;
  int grA0 = m0 + ln;      grA0 = grA0 < M ? grA0 : M - 1;
  int grA1 = m0 + 64 + ln; grA1 = grA1 < M ? grA1 : M - 1;
  int grW = n0 + ln;       grW = grW < N ? grW : N - 1;
  const float* srcA0 = A + (size_t)grA0 * K + wv * 4;
  const float* srcA1 = A + (size_t)grA1 * K + wv * 4;
  const float* srcW = W + (size_t)grW * K + wv * 4;
  const unsigned dmaA = (unsigned)wv * 2048u;          // quad base in A
  const unsigned dmaW = 16384u + (unsigned)wv * 1024u; // quad base in W

#define ISSUE(CH, BUF)                                                 \
  {                                                                    \
    const int _kk = (CH)*BK;                                           \
    unsigned char* _b = pool + (BUF)*24576u;                           \
    GLOAD16(srcA0 + _kk, _b + dmaA);                                   \
    GLOAD16(srcA1 + _kk, _b + dmaA + 1024);                            \
    GLOAD16(srcW + _kk, _b + dmaW);                                    \
  }

  // ---- accumulators ----
  float vmax[4][4], vmin[4][4];
  int pmax[4][4], pmin[4][4];  // 8-k window of first occurrence (0..K/8-1)
#pragma unroll
  for (int i = 0; i < 4; ++i)
#pragma unroll
    for (int j = 0; j < 4; ++j) {
      vmax[i][j] = -FLT_MAX;
      vmin[i][j] = FLT_MAX;
      pmax[i][j] = 0;
      pmin[i][j] = 0;
    }

  const int nchunk = K / BK;

  // A read: quad q, row ty*4+i -> byte q*2048 + (ty*4+i)*16
  // W read: quad q, row tx+16j -> byte 16384 + q*1024 + tx*16 + j*256
#define ARD(KQ, I) (*(const f32x4*)(Ab + (KQ)*2048 + (I)*16))
#define WRD(KQ, J) (*(const f32x4*)(Wb + (KQ)*1024 + (J)*256))

#define TRK8(I, J, AV0, AV1, WV0, WV1)                                 \
  {                                                                    \
    const f32x2 q0 = pk_mul((AV0).xy, (WV0).xy);                       \
    const f32x2 q1 = pk_mul((AV0).zw, (WV0).zw);                       \
    float c = vmax3(vmax[I][J], q0.x, q0.y);                           \
    float d = vmin3(vmin[I][J], q0.x, q0.y);                           \
    c = vmax3(c, q1.x, q1.y);                                          \
    d = vmin3(d, q1.x, q1.y);                                          \
    const f32x2 q2 = pk_mul((AV1).xy, (WV1).xy);                       \
    const f32x2 q3 = pk_mul((AV1).zw, (WV1).zw);                       \
    c = vmax3(c, q2.x, q2.y);                                          \
    d = vmin3(d, q2.x, q2.y);                                          \
    c = vmax3(c, q3.x, q3.y);                                          \
    d = vmin3(d, q3.x, q3.y);                                          \
    pmax[I][J] = (c != vmax[I][J]) ? wnd : pmax[I][J];                 \
    vmax[I][J] = c;                                                    \
    pmin[I][J] = (d != vmin[I][J]) ? wnd : pmin[I][J];                 \
    vmin[I][J] = d;                                                    \
  }

  // ---- main loop: DMA double-buffered, one barrier per chunk ----
  ISSUE(0, 0)
  __syncthreads();
  int buf = 0;
  for (int ch = 0; ch < nchunk; ++ch) {
    if (ch + 1 < nchunk) ISSUE(ch + 1, buf ^ 1)
    const unsigned char* Ab = pool + (unsigned)buf * 24576u + ty * 64;
    const unsigned char* Wb = pool + (unsigned)buf * 24576u + 16384u + tx * 16;
#pragma unroll
    for (int h = 0; h < 4; ++h) {  // 8-k window: quads 2h, 2h+1
      const int wnd = ch * 4 + h;
      const f32x4 aA0 = ARD(2 * h, 0);
      const f32x4 aA1 = ARD(2 * h, 1);
      const f32x4 aA2 = ARD(2 * h, 2);
      const f32x4 aA3 = ARD(2 * h, 3);
      const f32x4 aB0 = ARD(2 * h + 1, 0);
      const f32x4 aB1 = ARD(2 * h + 1, 1);
      const f32x4 aB2 = ARD(2 * h + 1, 2);
      const f32x4 aB3 = ARD(2 * h + 1, 3);
#pragma unroll
      for (int j = 0; j < 4; ++j) {
        const f32x4 w0 = WRD(2 * h, j);
        const f32x4 w1 = WRD(2 * h + 1, j);
        TRK8(0, j, aA0, aB0, w0, w1)
        TRK8(1, j, aA1, aB1, w0, w1)
        TRK8(2, j, aA2, aB2, w0, w1)
        TRK8(3, j, aA3, aB3, w0, w1)
      }
    }
    __syncthreads();
    buf ^= 1;
  }

  // ---- epilogue: values + within-window argmax from global (L2/L3-hot) ----
#pragma unroll
  for (int i = 0; i < 4; ++i) {
    const int gm = m0 + ty * 4 + i;
    if (gm >= M) continue;
    const size_t arow = (size_t)gm * K;
#pragma unroll
    for (int j = 0; j < 4; ++j) {
      const int gn = n0 + tx + 16 * j;
      if (gn >= N) continue;
      const size_t wrow = (size_t)gn * K;
      const size_t base = (size_t)gm * N + gn;
      out_v[base] = vmax[i][j] + vmin[i][j] + bias[gn];
      {  // max side
        const int kb = pmax[i][j] * 8;
        const f32x4 a0 = *(const f32x4*)(A + arow + kb);
        const f32x4 a1 = *(const f32x4*)(A + arow + kb + 4);
        const f32x4 w0 = *(const f32x4*)(W + wrow + kb);
        const f32x4 w1 = *(const f32x4*)(W + wrow + kb + 4);
        float cur = -FLT_MAX; int pos = 0; float p;
        p = a0.x * w0.x; if (p > cur) { cur = p; pos = 0; }
        p = a0.y * w0.y; if (p > cur) { cur = p; pos = 1; }
        p = a0.z * w0.z; if (p > cur) { cur = p; pos = 2; }
        p = a0.w * w0.w; if (p > cur) { cur = p; pos = 3; }
        p = a1.x * w1.x; if (p > cur) { cur = p; pos = 4; }
        p = a1.y * w1.y; if (p > cur) { cur = p; pos = 5; }
        p = a1.z * w1.z; if (p > cur) { cur = p; pos = 6; }
        p = a1.w * w1.w; if (p > cur) { cur = p; pos = 7; }
        out_ax[base] = (float)(kb + pos);
      }
      {  // min side
        const int kb = pmin[i][j] * 8;
        const f32x4 a0 = *(const f32x4*)(A + arow + kb);
        const f32x4 a1 = *(const f32x4*)(A + arow + kb + 4);
        const f32x4 w0 = *(const f32x4*)(W + wrow + kb);
        const f32x4 w1 = *(const f32x4*)(W + wrow + kb + 4);
        float cur = FLT_MAX; int pos = 0; float p;
        p = a0.x * w0.x; if (p < cur) { cur = p; pos = 0; }
        p = a0.y * w0.y; if (p < cur) { cur = p; pos = 1; }
        p = a0.z * w0.z; if (p < cur) { cur = p; pos = 2; }
        p = a0.w * w0.w; if (p < cur) { cur = p; pos = 3; }
        p = a1.x * w1.x; if (p < cur) { cur = p; pos = 4; }
        p = a1.y * w1.y; if (p < cur) { cur = p; pos = 5; }
        p = a1.z * w1.z; if (p < cur) { cur = p; pos = 6; }
        p = a1.w * w1.w; if (p < cur) { cur = p; pos = 7; }
        out_an[base] = (float)(kb + pos);
      }
    }
  }
}

extern "C" void kernel_launch(void* const* d_in, const int* in_sizes, int n_in,
                              void* d_out, int out_size, void* d_ws, size_t ws_size,
                              hipStream_t stream) {
  const float* A = (const float*)d_in[0];     // [M, K] fp32
  const float* W = (const float*)d_in[1];     // [N, K] fp32
  const float* bias = (const float*)d_in[2];  // [N]    fp32
  const int N = in_sizes[2];
  const int K = in_sizes[1] / N;
  const int M = in_sizes[0] / K;
  float* out_v = (float*)d_out;
  float* out_ax = out_v + (size_t)M * N;
  float* out_an = out_v + 2 * (size_t)M * N;
  dim3 grid((N + BN - 1) / BN, (M + BM - 1) / BM);
  mam_fused<<<grid, dim3(512), 0, stream>>>(A, W, bias, out_v, out_ax, out_an,
                                            M, N, K);
}